// Round 1
// 238.418 us; speedup vs baseline: 1.0080x; 1.0080x over previous
//
#include <hip/hip_runtime.h>
#include <hip/hip_bf16.h>

// Problem dims (fixed by reference)
#define BB 8
#define NN 2048
#define DD 256
#define MM (BB * NN)   // 16384 rows

typedef __attribute__((ext_vector_type(8))) short bf16x8_t;  // 8 bf16 = 4 VGPRs
typedef __attribute__((ext_vector_type(4))) float f32x4_t;

// ---------------------------------------------------------------------------
// Kernel A (fused): h = x @ W^T + b, PLUS the per-row attention dots
//   s1b[row] = h_rounded @ a1 + att_b
//   t2[row]  = mask[row] ? h_rounded @ a2 : -1e30
// computed from the SAME bf16-rounded h values that are stored to global, so
// numerics match the previous (passing) gemm_h + s_kernel pair exactly.
//
// grid 256 (= M/64), block 512 (8 waves). Each block owns a full 64x256
// output strip: x tile read ONCE (vs 4x before), Wt is an L2/L3 broadcast.
// Wave w: rows (w&3)*16, col-half (w>>2)*128. Register prefetch of the next
// K-tile overlaps the global loads with the MFMA of the current tile.
// ---------------------------------------------------------------------------
__global__ __launch_bounds__(512) void gemm_hs(
    const float* __restrict__ x,     // [M,256] fp32
    const float* __restrict__ Wt,    // [256,256] fp32 row-major [out,in] (B^T form)
    const float* __restrict__ bias,  // [256] fp32
    const float* __restrict__ a1,    // [256]
    const float* __restrict__ a2,    // [256]
    const float* __restrict__ mask,  // [M]
    const float* __restrict__ attb_p,
    __hip_bfloat16* __restrict__ h,  // [M,256] bf16
    float* __restrict__ s1b,         // [M]
    float* __restrict__ t2)          // [M]
{
    __shared__ __hip_bfloat16 As[64][72];    //  9.2 KB
    __shared__ __hip_bfloat16 Bs[256][72];   // 36.9 KB
    __shared__ float s_p1[64], s_p2[64];

    const int tid  = threadIdx.x;
    const int w    = tid >> 6;          // wave 0..7
    const int lane = tid & 63;
    const int m16  = lane & 15;
    const int quad = lane >> 4;
    const int rg   = w & 3;             // row group: rows rg*16 .. rg*16+15
    const int cg   = w >> 2;            // col half: cols cg*128 .. cg*128+127
    const long rowBase = (long)blockIdx.x * 64;

    // staging assignment (512 threads)
    const int ar = tid >> 3;            // x row 0..63
    const int ac = (tid & 7) * 8;       // 8 floats  (2 float4)
    const int br = tid >> 1;            // Wt row 0..255
    const int bc = (tid & 1) * 32;      // 32 floats (8 float4)

    f32x4_t acc[8];
#pragma unroll
    for (int c = 0; c < 8; c++) acc[c] = (f32x4_t){0.f, 0.f, 0.f, 0.f};

    // prefetch K-tile 0 into registers
    float4 av[2], bv[8];
    {
        const float4* ag = (const float4*)(x + (rowBase + ar) * 256 + ac);
        av[0] = ag[0]; av[1] = ag[1];
        const float4* bg = (const float4*)(Wt + (long)br * 256 + bc);
#pragma unroll
        for (int q = 0; q < 8; q++) bv[q] = bg[q];
    }

    for (int k0 = 0; k0 < 256; k0 += 64) {
        // convert the prefetched tile to bf16
        __align__(16) __hip_bfloat16 ta[8];
        __align__(16) __hip_bfloat16 tb[32];
#pragma unroll
        for (int q = 0; q < 2; q++) {
            ta[q * 4 + 0] = __float2bfloat16(av[q].x);
            ta[q * 4 + 1] = __float2bfloat16(av[q].y);
            ta[q * 4 + 2] = __float2bfloat16(av[q].z);
            ta[q * 4 + 3] = __float2bfloat16(av[q].w);
        }
#pragma unroll
        for (int q = 0; q < 8; q++) {
            tb[q * 4 + 0] = __float2bfloat16(bv[q].x);
            tb[q * 4 + 1] = __float2bfloat16(bv[q].y);
            tb[q * 4 + 2] = __float2bfloat16(bv[q].z);
            tb[q * 4 + 3] = __float2bfloat16(bv[q].w);
        }

        __syncthreads();   // readers of previous tile done
        *(uint4*)&As[ar][ac] = *(uint4*)&ta[0];
#pragma unroll
        for (int q = 0; q < 4; q++)
            *(uint4*)&Bs[br][bc + q * 8] = *(uint4*)&tb[q * 8];
        __syncthreads();   // tile visible

        // issue next tile's global loads: overlap with MFMA below
        if (k0 < 192) {
            const int kn = k0 + 64;
            const float4* ag = (const float4*)(x + (rowBase + ar) * 256 + kn + ac);
            av[0] = ag[0]; av[1] = ag[1];
            const float4* bg = (const float4*)(Wt + (long)br * 256 + kn + bc);
#pragma unroll
            for (int q = 0; q < 8; q++) bv[q] = bg[q];
        }

#pragma unroll
        for (int kk = 0; kk < 64; kk += 32) {
            bf16x8_t af = *(const bf16x8_t*)&As[rg * 16 + m16][kk + quad * 8];
#pragma unroll
            for (int c = 0; c < 8; c++) {
                bf16x8_t bf = *(const bf16x8_t*)&Bs[cg * 128 + c * 16 + m16][kk + quad * 8];
                acc[c] = __builtin_amdgcn_mfma_f32_16x16x32_bf16(af, bf, acc[c], 0, 0, 0);
            }
        }
    }

    // ---- epilogue: store h (bf16) and accumulate the a1/a2 dots from the
    //      SAME rounded values. C/D layout: col = m16 (+c*16), row = quad*4+reg.
    const int colBase = cg * 128;
    float p1[4] = {0.f, 0.f, 0.f, 0.f};
    float p2[4] = {0.f, 0.f, 0.f, 0.f};
    const long rw0 = rowBase + rg * 16 + quad * 4;
#pragma unroll
    for (int c = 0; c < 8; c++) {
        const int col = colBase + c * 16 + m16;
        const float bval = bias[col];
        const float va1  = a1[col];
        const float va2  = a2[col];
#pragma unroll
        for (int reg = 0; reg < 4; reg++) {
            const __hip_bfloat16 hv = __float2bfloat16(acc[c][reg] + bval);
            h[(rw0 + reg) * 256 + col] = hv;
            const float hr = __bfloat162float(hv);
            p1[reg] += hr * va1;
            p2[reg] += hr * va2;
        }
    }
    // reduce across the 16 m16-lanes (covers this wave's 128 cols)
#pragma unroll
    for (int off = 1; off < 16; off <<= 1) {
#pragma unroll
        for (int reg = 0; reg < 4; reg++) {
            p1[reg] += __shfl_xor(p1[reg], off);
            p2[reg] += __shfl_xor(p2[reg], off);
        }
    }
    // cross-wave combine: col-half 1 publishes, col-half 0 finishes
    if (cg == 1 && m16 == 0) {
#pragma unroll
        for (int reg = 0; reg < 4; reg++) {
            s_p1[rg * 16 + quad * 4 + reg] = p1[reg];
            s_p2[rg * 16 + quad * 4 + reg] = p2[reg];
        }
    }
    __syncthreads();
    if (cg == 0 && m16 == 0) {
        const float ab = attb_p[0];
#pragma unroll
        for (int reg = 0; reg < 4; reg++) {
            const int rl = rg * 16 + quad * 4 + reg;
            const long row = rowBase + rl;
            const float sp1 = p1[reg] + s_p1[rl];
            const float sp2 = p2[reg] + s_p2[rl];
            s1b[row] = sp1 + ab;
            t2[row]  = (mask[row] != 0.f) ? sp2 : -1e30f;
        }
    }
}

// ---------------------------------------------------------------------------
// Kernel C: sparse attention aggregate. One block per (b,i) row, 256 threads.
// (UNCHANGED from the 238.5 µs version — kept byte-identical so the delta
//  attributes cleanly to the fused GEMM.)
// ---------------------------------------------------------------------------
__global__ __launch_bounds__(256) void attn_agg(
    const float* __restrict__ adj,
    const float* __restrict__ mask,
    const __hip_bfloat16* __restrict__ h,
    const float* __restrict__ s1b,
    const float* __restrict__ t2,
    float* __restrict__ out)
{
    __shared__ float2 s_list[1024];   // .x = byte offset (j<<9) as int bits, .y = weight
    __shared__ int    s_cnt;
    __shared__ float  s_red[4];
    __shared__ float  s_inv;
    __shared__ float2 s_part[128];

    const int tid = threadIdx.x;
    const int b   = blockIdx.x & 7;
    const int i   = blockIdx.x >> 3;
    const long row   = (long)b * NN + i;
    const long mbase = (long)b * NN;

    const float mask_i = mask[row];
    if (mask_i == 0.f) {                  // block-uniform early exit (no barriers yet)
        out[row * 256 + tid] = 0.f;
        return;
    }
    if (tid == 0) s_cnt = 0;
    __syncthreads();

    const float si = s1b[row];
    const float4* arow = (const float4*)(adj + row * NN);
    const float4* trow = (const float4*)(t2 + mbase);

    float4 A0 = arow[tid], A1 = arow[256 + tid];   // coalesced: j = tid*4.. / 1024+tid*4..
    float4 T0 = trow[tid], T1 = trow[256 + tid];   // L1-resident (64 KB array)

    float lsum = 0.f;
#pragma unroll
    for (int g = 0; g < 2; g++) {
        const int jb = g * 1024 + tid * 4;
        const float av[4] = {g ? A1.x : A0.x, g ? A1.y : A0.y, g ? A1.z : A0.z, g ? A1.w : A0.w};
        const float tv[4] = {g ? T1.x : T0.x, g ? T1.y : T0.y, g ? T1.z : T0.z, g ? T1.w : T0.w};
#pragma unroll
        for (int e = 0; e < 4; e++) {
            const float z   = si + tv[e];
            const float sig = __builtin_amdgcn_rcpf(1.f + __expf(-z));  // rcp(inf)=0 for masked j
            const float wgt = av[e] * sig;
            lsum += wgt;
            if (wgt != 0.f) {             // exec-masked append, ~1 active lane/wave-iter
                const int pos = atomicAdd(&s_cnt, 1);
                if (pos < 1024)
                    s_list[pos] = make_float2(__int_as_float((jb + e) << 9), wgt);
            }
        }
    }

    // ---- denominator: wave shuffle-reduce + cross-wave via LDS ----
#pragma unroll
    for (int off = 32; off; off >>= 1) lsum += __shfl_down(lsum, off);
    const int lane = tid & 63, wv = tid >> 6;
    if (lane == 0) s_red[wv] = lsum;
    __syncthreads();
    if (tid == 0)
        s_inv = 1.f / (s_red[0] + s_red[1] + s_red[2] + s_red[3] + 1e-8f);
    __syncthreads();

    // ---- gather: group g takes a contiguous half of the list; thread owns
    //      channel pair {2t, 2t+1} via one dword load per neighbor ----
    const int cnt  = min(s_cnt, 1024);
    const float inv = s_inv * mask_i;     // mask_i==1 for valid rows (binary mask)
    const char* hb = (const char*)(h + mbase * 256);   // block-uniform -> SGPR base
    const int g  = tid >> 7;
    const int t  = tid & 127;
    const int t4 = t * 4;
    const int half = (cnt + 1) >> 1;
    int k       = g ? half : 0;
    const int end = g ? cnt : half;

    float accx = 0.f, accy = 0.f;
    for (; k + 8 <= end; k += 8) {
        float2 e[8];
#pragma unroll
        for (int q = 0; q < 8; q++) e[q] = s_list[k + q];      // wave-uniform: broadcast
        unsigned u[8];
#pragma unroll
        for (int q = 0; q < 8; q++)
            u[q] = *(const unsigned*)(hb + (__float_as_int(e[q].x) + t4));
#pragma unroll
        for (int q = 0; q < 8; q++) {
            accx += e[q].y * __uint_as_float(u[q] << 16);
            accy += e[q].y * __uint_as_float(u[q] & 0xffff0000u);
        }
    }
    for (; k + 4 <= end; k += 4) {
        float2 e[4];
#pragma unroll
        for (int q = 0; q < 4; q++) e[q] = s_list[k + q];
        unsigned u[4];
#pragma unroll
        for (int q = 0; q < 4; q++)
            u[q] = *(const unsigned*)(hb + (__float_as_int(e[q].x) + t4));
#pragma unroll
        for (int q = 0; q < 4; q++) {
            accx += e[q].y * __uint_as_float(u[q] << 16);
            accy += e[q].y * __uint_as_float(u[q] & 0xffff0000u);
        }
    }
    for (; k < end; k++) {
        float2 ee = s_list[k];
        unsigned u = *(const unsigned*)(hb + (__float_as_int(ee.x) + t4));
        accx += ee.y * __uint_as_float(u << 16);
        accy += ee.y * __uint_as_float(u & 0xffff0000u);
    }

    // combine the two groups' partial sums, group 0 writes float2
    if (g) s_part[t] = make_float2(accx, accy);
    __syncthreads();
    if (!g) {
        const float2 p = s_part[t];
        ((float2*)(out + row * 256))[t] =
            make_float2((accx + p.x) * inv, (accy + p.y) * inv);
    }
}

// ---------------------------------------------------------------------------
extern "C" void kernel_launch(void* const* d_in, const int* in_sizes, int n_in,
                              void* d_out, int out_size, void* d_ws, size_t ws_size,
                              hipStream_t stream) {
    const float* x    = (const float*)d_in[0];
    const float* adj  = (const float*)d_in[1];
    const float* mask = (const float*)d_in[2];
    const float* W    = (const float*)d_in[3];
    const float* bias = (const float*)d_in[4];
    const float* a1   = (const float*)d_in[5];
    const float* a2   = (const float*)d_in[6];
    const float* attb = (const float*)d_in[7];
    float* out = (float*)d_out;

    // workspace: h bf16 [16384*256] (8 MB) | s1b fp32 [16384] | t2 fp32 [16384]
    __hip_bfloat16* h = (__hip_bfloat16*)d_ws;
    float* s1b = (float*)((char*)d_ws + (size_t)MM * DD * 2);
    float* t2  = s1b + MM;

    gemm_hs<<<MM / 64, 512, 0, stream>>>(x, W, bias, a1, a2, mask, attb, h, s1b, t2);
    attn_agg<<<MM, 256, 0, stream>>>(adj, mask, h, s1b, t2, out);
}